// Round 4
// baseline (295.372 us; speedup 1.0000x reference)
//
#include <hip/hip_runtime.h>

// HPWL: segmented min/max over CSR nets + masked sum.
// NOTE: harness passes integer inputs as int32 (JAX default no-x64 downcasts
// the reference's int64 arrays). Reading them as int64 fused index pairs into
// garbage addresses -> the R1-R3 core dumps.
//
// Deterministic two-stage reduction:
//   stage 1: fixed 1024-block grid, grid-stride over nets, one partial/block -> d_ws
//   stage 2: single block reduces the 1024 partials, plain store to out[0].
// No atomics -> identical result on every rocprof replay.

#define S1_BLOCKS 1024
#define S1_THREADS 256

__global__ __launch_bounds__(S1_THREADS) void hpwl_stage1(
    const float* __restrict__ pos,
    const int* __restrict__ flat_netpin,
    const int* __restrict__ netpin_start,
    const int* __restrict__ ignore_p,
    float* __restrict__ partials,
    int num_nets, int num_pins)
{
    const int ignore = ignore_p[0];
    const int stride = gridDim.x * blockDim.x;

    float acc = 0.0f;
    for (int net = blockIdx.x * blockDim.x + threadIdx.x; net < num_nets; net += stride) {
        const int s = netpin_start[net];
        const int e = netpin_start[net + 1];
        const int deg = e - s;
        if (deg > 0 && deg <= ignore) {
            float xmin =  3.4e38f, xmax = -3.4e38f;
            float ymin =  3.4e38f, ymax = -3.4e38f;
            for (int i = s; i < e; ++i) {
                const int p = flat_netpin[i];
                const float x = pos[p];
                const float y = pos[num_pins + p];
                xmin = fminf(xmin, x); xmax = fmaxf(xmax, x);
                ymin = fminf(ymin, y); ymax = fmaxf(ymax, y);
            }
            acc += (xmax - xmin) + (ymax - ymin);
        }
    }

    // wave(64) shuffle reduction
    #pragma unroll
    for (int off = 32; off > 0; off >>= 1)
        acc += __shfl_down(acc, off, 64);

    __shared__ float lds[S1_THREADS / 64];
    const int lane = threadIdx.x & 63;
    const int wave = threadIdx.x >> 6;
    if (lane == 0) lds[wave] = acc;
    __syncthreads();
    if (threadIdx.x == 0) {
        float t = 0.0f;
        #pragma unroll
        for (int w = 0; w < S1_THREADS / 64; ++w) t += lds[w];
        partials[blockIdx.x] = t;
    }
}

__global__ __launch_bounds__(256) void hpwl_stage2(
    const float* __restrict__ partials, float* __restrict__ out, int n)
{
    float acc = 0.0f;
    for (int i = threadIdx.x; i < n; i += 256) acc += partials[i];

    #pragma unroll
    for (int off = 32; off > 0; off >>= 1)
        acc += __shfl_down(acc, off, 64);

    __shared__ float lds[4];
    const int lane = threadIdx.x & 63;
    const int wave = threadIdx.x >> 6;
    if (lane == 0) lds[wave] = acc;
    __syncthreads();
    if (threadIdx.x == 0)
        out[0] = (lds[0] + lds[1]) + (lds[2] + lds[3]);
}

extern "C" void kernel_launch(void* const* d_in, const int* in_sizes, int n_in,
                              void* d_out, int out_size, void* d_ws, size_t ws_size,
                              hipStream_t stream) {
    (void)n_in; (void)out_size; (void)ws_size;
    const float* pos          = (const float*)d_in[0];
    const int*   flat_netpin  = (const int*)d_in[1];
    const int*   netpin_start = (const int*)d_in[2];
    const int*   ignore_p     = (const int*)d_in[3];
    float*       out          = (float*)d_out;
    float*       partials     = (float*)d_ws;   // 4 KB used

    const int num_pins = in_sizes[1];
    const int num_nets = in_sizes[2] - 1;

    hpwl_stage1<<<dim3(S1_BLOCKS), dim3(S1_THREADS), 0, stream>>>(
        pos, flat_netpin, netpin_start, ignore_p, partials, num_nets, num_pins);
    hpwl_stage2<<<dim3(1), dim3(256), 0, stream>>>(partials, out, S1_BLOCKS);
}

// Round 5
// 289.394 us; speedup vs baseline: 1.0207x; 1.0207x over previous
//
#include <hip/hip_runtime.h>

// HPWL: segmented min/max over CSR nets + masked sum.
// int32 inputs (JAX no-x64 downcast). Deterministic two-stage reduction.
//
// R5: one thread per net, full launch (no grid-stride), and a predicated
// unroll-by-8 gather (clamped duplicate index -> idempotent for min/max,
// same-line L1 hit) so each thread issues 8 independent flat loads then 16
// independent pos gathers instead of a serial dependent loop. This is the
// MLP fix for the latency-bound profile (VALUBusy 2.3%, occupancy 40%).

#define S1_THREADS 256
#define MAXDEG 8

__global__ __launch_bounds__(S1_THREADS) void hpwl_stage1(
    const float* __restrict__ pos,
    const int* __restrict__ flat_netpin,
    const int* __restrict__ netpin_start,
    const int* __restrict__ ignore_p,
    float* __restrict__ partials,
    int num_nets, int num_pins)
{
    const int net = blockIdx.x * blockDim.x + threadIdx.x;
    const int ignore = ignore_p[0];

    float acc = 0.0f;
    if (net < num_nets) {
        const int s = netpin_start[net];
        const int e = netpin_start[net + 1];
        const int deg = e - s;
        if (deg > 0 && deg <= ignore) {
            if (deg <= MAXDEG) {
                // 8 independent index loads (k>=deg clamps to deg-1: duplicate
                // address, idempotent for min/max, guaranteed cache hit)
                int idx[MAXDEG];
                #pragma unroll
                for (int k = 0; k < MAXDEG; ++k) {
                    const int j = (k < deg) ? k : (deg - 1);
                    idx[k] = __builtin_nontemporal_load(flat_netpin + s + j);
                }
                // 16 independent gathers
                float xv[MAXDEG], yv[MAXDEG];
                #pragma unroll
                for (int k = 0; k < MAXDEG; ++k) {
                    xv[k] = pos[idx[k]];
                    yv[k] = pos[num_pins + idx[k]];
                }
                float xmin = xv[0], xmax = xv[0];
                float ymin = yv[0], ymax = yv[0];
                #pragma unroll
                for (int k = 1; k < MAXDEG; ++k) {
                    xmin = fminf(xmin, xv[k]); xmax = fmaxf(xmax, xv[k]);
                    ymin = fminf(ymin, yv[k]); ymax = fmaxf(ymax, yv[k]);
                }
                acc = (xmax - xmin) + (ymax - ymin);
            } else {
                // generic fallback (not hit for this input: live deg <= 7)
                float xmin =  3.4e38f, xmax = -3.4e38f;
                float ymin =  3.4e38f, ymax = -3.4e38f;
                for (int i = s; i < e; ++i) {
                    const int p = flat_netpin[i];
                    const float x = pos[p];
                    const float y = pos[num_pins + p];
                    xmin = fminf(xmin, x); xmax = fmaxf(xmax, x);
                    ymin = fminf(ymin, y); ymax = fmaxf(ymax, y);
                }
                acc = (xmax - xmin) + (ymax - ymin);
            }
        }
    }

    // wave(64) shuffle reduction
    #pragma unroll
    for (int off = 32; off > 0; off >>= 1)
        acc += __shfl_down(acc, off, 64);

    __shared__ float lds[S1_THREADS / 64];
    const int lane = threadIdx.x & 63;
    const int wave = threadIdx.x >> 6;
    if (lane == 0) lds[wave] = acc;
    __syncthreads();
    if (threadIdx.x == 0) {
        float t = 0.0f;
        #pragma unroll
        for (int w = 0; w < S1_THREADS / 64; ++w) t += lds[w];
        partials[blockIdx.x] = t;
    }
}

__global__ __launch_bounds__(256) void hpwl_stage2(
    const float* __restrict__ partials, float* __restrict__ out, int n)
{
    float acc = 0.0f;
    for (int i = threadIdx.x; i < n; i += 256) acc += partials[i];

    #pragma unroll
    for (int off = 32; off > 0; off >>= 1)
        acc += __shfl_down(acc, off, 64);

    __shared__ float lds[4];
    const int lane = threadIdx.x & 63;
    const int wave = threadIdx.x >> 6;
    if (lane == 0) lds[wave] = acc;
    __syncthreads();
    if (threadIdx.x == 0)
        out[0] = (lds[0] + lds[1]) + (lds[2] + lds[3]);
}

extern "C" void kernel_launch(void* const* d_in, const int* in_sizes, int n_in,
                              void* d_out, int out_size, void* d_ws, size_t ws_size,
                              hipStream_t stream) {
    (void)n_in; (void)out_size; (void)ws_size;
    const float* pos          = (const float*)d_in[0];
    const int*   flat_netpin  = (const int*)d_in[1];
    const int*   netpin_start = (const int*)d_in[2];
    const int*   ignore_p     = (const int*)d_in[3];
    float*       out          = (float*)d_out;
    float*       partials     = (float*)d_ws;   // grid * 4 bytes (~22 KB)

    const int num_pins = in_sizes[1];
    const int num_nets = in_sizes[2] - 1;

    const int grid = (num_nets + S1_THREADS - 1) / S1_THREADS;  // one net/thread
    hpwl_stage1<<<dim3(grid), dim3(S1_THREADS), 0, stream>>>(
        pos, flat_netpin, netpin_start, ignore_p, partials, num_nets, num_pins);
    hpwl_stage2<<<dim3(1), dim3(256), 0, stream>>>(partials, out, grid);
}